// Round 13
// baseline (488.982 us; speedup 1.0000x reference)
//
#include <hip/hip_runtime.h>
#include <hip/hip_bf16.h>

typedef __attribute__((ext_vector_type(8))) short short8;
typedef __attribute__((ext_vector_type(4))) float f32x4;

#define NTOK   4096
#define EDIM   768
#define HFF_   2048
#define MAXR   9216          // 4096*2 pairs + 8*128 alignment pad

// ---- workspace layout (float offsets) ----
#define OFF_Q      0
#define OFF_K      3145728
#define OFF_V      6291456
#define OFF_S      9437184          // s_buf: 12.58M -> ends 22,020,096
#define OFF_PRJ    OFF_S            // prj overlays s region (s dead when prj written)
#define OFF_ASPLIT 22020096         // asp planes -> ends 25,165,824 (no overlap with s_buf)
#define OFF_X1     25165824
#define OFF_X2     28311552
#define OFF_WT     31457280
#define OFF_INT    33226752
// MoE overlay (attention buffers dead):
#define OFF_HID    0
#define OFF_WVT    9437184
#define OFF_WGT    15728640
#define OFF_AMOE   22020096         // overwrites asp only after its last read
#define OFF_WOT    9437184
#define OFF_POUT   15728640

// ---------------- helpers ----------------

__device__ __forceinline__ short f2bf(float f) {
  union { float f; unsigned u; } c; c.f = f;
  unsigned r = (c.u + 0x7fffu + ((c.u >> 16) & 1u)) >> 16;   // RNE
  return (short)r;
}

__device__ __forceinline__ float bf2f(short s) {
  union { unsigned u; float f; } c; c.u = ((unsigned)(unsigned short)s) << 16;
  return c.f;
}

__device__ __forceinline__ void split2(float f, short& h, short& l) {
  short hs = f2bf(f);
  union { unsigned u; float fl; } hv; hv.u = ((unsigned)(unsigned short)hs) << 16;
  h = hs;
  l = f2bf(f - hv.fl);
}

// async 16B/lane global->LDS (dest = uniform base + lane*16)
__device__ __forceinline__ void gload16(const short* g, short* l) {
  __builtin_amdgcn_global_load_lds(
      (const __attribute__((address_space(1))) void*)g,
      (__attribute__((address_space(3))) void*)l, 16, 0, 0);
}

// swizzled column within a 64-short K-chunk: slot' = slot ^ (row&7)
__device__ __forceinline__ int swzcol(int col, int row) {
  return (col & ~63) | ((((col >> 3) & 7) ^ (row & 7)) << 3) | (col & 7);
}

// read one 16B fragment at (row, logical slot) from a linear swizzled LDS tile [R][64]
__device__ __forceinline__ short8 frag(const short* lds, int row, int slot) {
  return *(const short8*)(lds + row * 64 + ((slot ^ (row & 7)) << 3));
}

// stage `rows` rows (chunk kt) of swizzled global matrix P (ld shorts/row) into linear LDS tile
__device__ __forceinline__ void stage_tile(const short* __restrict__ P, long grow0, int ld,
                                           int kt, short* lds, int rows, int wave, int lane) {
  for (int j = wave; j < (rows >> 3); j += 4) {
    const short* src = P + (size_t)(grow0 + j * 8 + (lane >> 3)) * ld + kt * 64 + (lane & 7) * 8;
    gload16(src, lds + (j << 9));
  }
}

// XCD-banded work map: XCD x owns NRP consecutive r-chunks, sweeps n inside.
template<int NRP>
__device__ __forceinline__ void xcd_map(int bid, int& r, int& n) {
  int xcd = bid & 7, sid = bid >> 3;
  n = sid / NRP;
  r = xcd * NRP + (sid - n * NRP);
}

// stage 64(rows) x 32(k) fp32 tile -> hi/lo bf16 LDS [64][40] (attention GEMMs only)
__device__ __forceinline__ void stage_rm2(const float* __restrict__ src, int ld,
                                          short (*hi)[40], short (*lo)[40], int tid) {
  int r = tid >> 2;
  int c = (tid & 3) << 3;
  const float* p = src + (size_t)r * ld + c;
  float4 a = *(const float4*)p;
  float4 b = *(const float4*)(p + 4);
  float f[8] = {a.x, a.y, a.z, a.w, b.x, b.y, b.z, b.w};
  short8 vh, vl;
  #pragma unroll
  for (int j = 0; j < 8; ++j) { short h, l; split2(f[j], h, l); vh[j] = h; vl[j] = l; }
  *(short8*)&hi[r][c] = vh;
  *(short8*)&lo[r][c] = vl;
}

// ---------------- weight split+transpose: w[768][768] -> hi/lo [768 n][768 k], swizzled ----------------
__global__ __launch_bounds__(256) void conv_split_T(
    const float* __restrict__ w, short* __restrict__ hi, short* __restrict__ lo) {
  __shared__ float tile[64][65];
  int tid = threadIdx.x;
  int k0 = blockIdx.x * 64, n0 = blockIdx.y * 64;
  int c = tid & 63, rg = tid >> 6;
  #pragma unroll
  for (int i = 0; i < 16; ++i) {
    int r = rg * 16 + i;
    tile[r][c] = w[(size_t)(k0 + r) * 768 + n0 + c];
  }
  __syncthreads();
  #pragma unroll
  for (int i = 0; i < 16; ++i) {
    int r = rg * 16 + i;
    int n = n0 + r;
    float f = tile[c][r];
    short h, l; split2(f, h, l);
    int cs = ((((c >> 3) ^ (n & 7)) << 3)) | (c & 7);
    hi[(size_t)n * 768 + k0 + cs] = h;
    lo[(size_t)n * 768 + k0 + cs] = l;
  }
}

// fused QKV variant: 3 weights -> one [2304 n][768 k] plane pair
__global__ __launch_bounds__(256) void conv_split_T3(
    const float* __restrict__ w0, const float* __restrict__ w1, const float* __restrict__ w2,
    short* __restrict__ hi, short* __restrict__ lo) {
  __shared__ float tile[64][65];
  const float* w = (blockIdx.z == 0) ? w0 : ((blockIdx.z == 1) ? w1 : w2);
  int nbase = blockIdx.z * 768;
  int tid = threadIdx.x;
  int k0 = blockIdx.x * 64, n0 = blockIdx.y * 64;
  int c = tid & 63, rg = tid >> 6;
  #pragma unroll
  for (int i = 0; i < 16; ++i) {
    int r = rg * 16 + i;
    tile[r][c] = w[(size_t)(k0 + r) * 768 + n0 + c];
  }
  __syncthreads();
  #pragma unroll
  for (int i = 0; i < 16; ++i) {
    int r = rg * 16 + i;
    int n = nbase + n0 + r;
    float f = tile[c][r];
    short h, l; split2(f, h, l);
    int cs = ((((c >> 3) ^ (n & 7)) << 3)) | (c & 7);
    hi[(size_t)n * 768 + k0 + cs] = h;
    lo[(size_t)n * 768 + k0 + cs] = l;
  }
}

// ---------------- transpose-convert: w[z][K][N] fp32 -> o[z][N][K] bf16, swizzled ----------------
__global__ __launch_bounds__(256) void conv_bf16_T(
    const float* __restrict__ w, short* __restrict__ o, int K, int N) {
  __shared__ float tile[64][65];
  int tid = threadIdx.x;
  int z = blockIdx.z;
  const float* wz = w + (size_t)z * K * N;
  short* oz = o + (size_t)z * K * N;
  int k0 = blockIdx.x * 64, n0 = blockIdx.y * 64;
  int c = tid & 63, rg = tid >> 6;
  #pragma unroll
  for (int i = 0; i < 16; ++i) {
    int r = rg * 16 + i;
    tile[r][c] = wz[(size_t)(k0 + r) * N + n0 + c];
  }
  __syncthreads();
  #pragma unroll
  for (int i = 0; i < 16; ++i) {
    int r = rg * 16 + i;
    int n = n0 + r;
    int cs = ((((c >> 3) ^ (n & 7)) << 3)) | (c & 7);
    oz[(size_t)n * K + k0 + cs] = f2bf(tile[c][r]);
  }
}

// ---------------- activation split: fp32 -> hi/lo bf16 planes, swizzled ----------------
__global__ __launch_bounds__(256) void asplit_kernel(
    const float* __restrict__ a, short* __restrict__ hi) {
  int i = (blockIdx.x * 256 + threadIdx.x) * 8;
  int row = i / 768, cc = i % 768;
  float4 f0 = *(const float4*)(a + i);
  float4 f1 = *(const float4*)(a + i + 4);
  float f[8] = {f0.x, f0.y, f0.z, f0.w, f1.x, f1.y, f1.z, f1.w};
  short8 h, l;
  #pragma unroll
  for (int j = 0; j < 8; ++j) { short hh, ll; split2(f[j], hh, ll); h[j] = hh; l[j] = ll; }
  int d = row * 768 + swzcol(cc, row);
  *(short8*)(hi + d) = h;
  *(short8*)(hi + NTOK * EDIM + d) = l;
}

// ---------------- projection GEMM v7: 128x128 tile, single acc[4][4], split operands, XCD-banded ----------------
template<int NRP>
__global__ __launch_bounds__(256) void proj_gemm_v7(
    const short* __restrict__ Asp, const short* __restrict__ wt, int wtotal,
    const float* __restrict__ b0, const float* __restrict__ b1, const float* __restrict__ b2,
    float* __restrict__ C0, float* __restrict__ C1, float* __restrict__ C2) {
  __shared__ short Ah[128 * 64], Al[128 * 64], Bh[128 * 64], Bl[128 * 64];   // 64 KB
  int tid = threadIdx.x, lane = tid & 63, wave = tid >> 6;
  int wr = wave >> 1, wc = wave & 1;
  int rblk, nblk;
  xcd_map<NRP>(blockIdx.x, rblk, nblk);
  int row0 = rblk * 128, col0 = nblk * 128;
  const short* alo = Asp + NTOK * EDIM;
  const short* wlo = wt + (size_t)wtotal * 768;
  f32x4 acc[4][4] = {};
  for (int kt = 0; kt < 12; ++kt) {
    stage_tile(Asp, row0, 768, kt, Ah, 128, wave, lane);
    stage_tile(alo, row0, 768, kt, Al, 128, wave, lane);
    stage_tile(wt,  col0, 768, kt, Bh, 128, wave, lane);
    stage_tile(wlo, col0, 768, kt, Bl, 128, wave, lane);
    __syncthreads();
    int lr = lane & 15, g4 = lane >> 4;
    #pragma unroll
    for (int ks = 0; ks < 2; ++ks) {
      int slot = ks * 4 + g4;
      short8 ah[4], al[4];
      #pragma unroll
      for (int m = 0; m < 4; ++m) {
        int row = wr * 64 + m * 16 + lr;
        ah[m] = frag(Ah, row, slot);
        al[m] = frag(Al, row, slot);
      }
      #pragma unroll
      for (int n = 0; n < 4; ++n) {
        int brow = wc * 64 + n * 16 + lr;
        short8 bh = frag(Bh, brow, slot);
        short8 bl = frag(Bl, brow, slot);
        #pragma unroll
        for (int m = 0; m < 4; ++m) {
          acc[m][n] = __builtin_amdgcn_mfma_f32_16x16x32_bf16(ah[m], bh, acc[m][n], 0, 0, 0);
          acc[m][n] = __builtin_amdgcn_mfma_f32_16x16x32_bf16(ah[m], bl, acc[m][n], 0, 0, 0);
          acc[m][n] = __builtin_amdgcn_mfma_f32_16x16x32_bf16(al[m], bh, acc[m][n], 0, 0, 0);
        }
      }
    }
    __syncthreads();
  }
  int seg = col0 / 768;
  const float* bp = (seg == 0) ? b0 : ((seg == 1) ? b1 : b2);
  float*       Cd = (seg == 0) ? C0 : ((seg == 1) ? C1 : C2);
  int cb = col0 - seg * 768;
  int lr = lane & 15, lg = lane >> 4;
  #pragma unroll
  for (int m = 0; m < 4; ++m)
    #pragma unroll
    for (int n = 0; n < 4; ++n) {
      int ccol = cb + wc * 64 + n * 16 + lr;
      float bv = bp[ccol];
      #pragma unroll
      for (int j = 0; j < 4; ++j) {
        int row = row0 + wr * 64 + m * 16 + lg * 4 + j;
        Cd[(size_t)row * 768 + ccol] = acc[m][n][j] + bv;
      }
    }
}

// ---------------- V transpose: v[bt][p][768] -> vT[bt*12+h][64][256] ----------------
__global__ __launch_bounds__(256) void v_transpose(
    const float* __restrict__ v, float* __restrict__ vT) {
  __shared__ float tile[64][65];
  int tid = threadIdx.x;
  int z = blockIdx.y;
  int bt = z / 12, h = z % 12;
  int p0 = blockIdx.x * 64;
  int c = tid & 63, rg = tid >> 6;
  #pragma unroll
  for (int i = 0; i < 16; ++i) {
    int r = rg * 16 + i;
    tile[r][c] = v[((size_t)bt * 256 + p0 + r) * 768 + h * 64 + c];
  }
  __syncthreads();
  #pragma unroll
  for (int i = 0; i < 16; ++i) {
    int r = rg * 16 + i;
    vT[((size_t)z * 64 + r) * 256 + p0 + c] = tile[c][r];
  }
}

// ---------------- attention GEMM (split, B^T); SPLITOUT writes hi/lo planes for AV ----------------
template<bool HAS_ALPHA, bool SPLITOUT>
__global__ __launch_bounds__(256) void attn_gemm_split(
    const float* __restrict__ A, int lda, long sA1, long sA2,
    const float* __restrict__ B, int ldb, long sB1, long sB2,
    float* __restrict__ C, int ldc, long sC1, long sC2,
    int K, int nz2, float alpha, short* __restrict__ sout) {
  __shared__ short Ah[64][40], Al[64][40], Bh[64][40], Bl[64][40];
  int tid = threadIdx.x;
  int lane = tid & 63, wave = tid >> 6;
  int wr = wave >> 1, wc = wave & 1;
  int z = blockIdx.z, z1 = z / nz2, z2 = z % nz2;
  const float* Ab = A + z1*sA1 + z2*sA2 + (size_t)blockIdx.x * 64 * lda;
  const float* Bb = B + z1*sB1 + z2*sB2 + (size_t)blockIdx.y * 64 * ldb;
  float* Cb = C + z1*sC1 + z2*sC2;
  f32x4 acc[2][2] = {};
  int nk = K >> 5;
  for (int kt = 0; kt < nk; ++kt) {
    stage_rm2(Ab + kt*32, lda, Ah, Al, tid);
    stage_rm2(Bb + kt*32, ldb, Bh, Bl, tid);
    __syncthreads();
    int lr = lane & 15, lk = (lane >> 4) * 8;
    short8 ah[2], al[2], bh[2], bl[2];
    #pragma unroll
    for (int m = 0; m < 2; ++m) {
      ah[m] = *(const short8*)&Ah[wr*32 + m*16 + lr][lk];
      al[m] = *(const short8*)&Al[wr*32 + m*16 + lr][lk];
    }
    #pragma unroll
    for (int n = 0; n < 2; ++n) {
      bh[n] = *(const short8*)&Bh[wc*32 + n*16 + lr][lk];
      bl[n] = *(const short8*)&Bl[wc*32 + n*16 + lr][lk];
    }
    #pragma unroll
    for (int m = 0; m < 2; ++m)
      #pragma unroll
      for (int n = 0; n < 2; ++n) {
        acc[m][n] = __builtin_amdgcn_mfma_f32_16x16x32_bf16(ah[m], bh[n], acc[m][n], 0, 0, 0);
        acc[m][n] = __builtin_amdgcn_mfma_f32_16x16x32_bf16(ah[m], bl[n], acc[m][n], 0, 0, 0);
        acc[m][n] = __builtin_amdgcn_mfma_f32_16x16x32_bf16(al[m], bh[n], acc[m][n], 0, 0, 0);
      }
    __syncthreads();
  }
  int lr = lane & 15, lg = lane >> 4;
  int row0 = blockIdx.x*64 + wr*32;
  int col0 = blockIdx.y*64 + wc*32;
  #pragma unroll
  for (int m = 0; m < 2; ++m)
    #pragma unroll
    for (int n = 0; n < 2; ++n) {
      int col = col0 + n*16 + lr;
      #pragma unroll
      for (int j = 0; j < 4; ++j) {
        int row = row0 + m*16 + lg*4 + j;
        float v = HAS_ALPHA ? acc[m][n][j]*alpha : acc[m][n][j];
        if (SPLITOUT) {
          // AV: z1 = bt (0..15), z2 = head; token = z1*256+row, channel = z2*64+col
          int tok = z1 * 256 + row;
          int c = z2 * 64 + col;
          short hh, ll; split2(v, hh, ll);
          int d = tok * 768 + swzcol(c, tok);
          sout[d] = hh;
          sout[NTOK * EDIM + d] = ll;
        } else {
          Cb[(size_t)row*ldc + col] = v;
        }
      }
    }
}

// ---------------- MoE GEMM 1: 128x64 tile, dual acc, XCD-banded ----------------
__global__ __launch_bounds__(256) void moe_gemm1_v6(
    const short* __restrict__ Am,
    const short* __restrict__ wvT, const short* __restrict__ wgT,
    const float* __restrict__ bv, const float* __restrict__ bg,
    const int* __restrict__ eoff, short* __restrict__ hidden) {
  int rblk, nblk;
  xcd_map<9>(blockIdx.x, rblk, nblk);
  int r0 = rblk * 128;
  if (r0 >= eoff[8]) return;
  int e = 0;
  #pragma unroll
  for (int q = 0; q < 8; ++q) if (r0 >= eoff[q] && r0 < eoff[q+1]) e = q;
  __shared__ short As[128 * 64], B1[64 * 64], B2[64 * 64];
  int tid = threadIdx.x, lane = tid & 63, wave = tid >> 6;
  int wr = wave >> 1, wc = wave & 1;
  int n0 = nblk * 64;
  const short* w1 = wvT + (size_t)e * 2048 * 768;
  const short* w2 = wgT + (size_t)e * 2048 * 768;
  f32x4 acc1[4][2] = {}, acc2[4][2] = {};
  for (int kt = 0; kt < 12; ++kt) {
    stage_tile(Am, r0, 768, kt, As, 128, wave, lane);
    stage_tile(w1, n0, 768, kt, B1, 64, wave, lane);
    stage_tile(w2, n0, 768, kt, B2, 64, wave, lane);
    __syncthreads();
    int lr = lane & 15, g4 = lane >> 4;
    #pragma unroll
    for (int ks = 0; ks < 2; ++ks) {
      int slot = ks * 4 + g4;
      short8 a[4], b1[2], b2[2];
      #pragma unroll
      for (int m = 0; m < 4; ++m) a[m] = frag(As, wr*64 + m*16 + lr, slot);
      #pragma unroll
      for (int n = 0; n < 2; ++n) {
        int row = wc*32 + n*16 + lr;
        b1[n] = frag(B1, row, slot);
        b2[n] = frag(B2, row, slot);
      }
      #pragma unroll
      for (int m = 0; m < 4; ++m)
        #pragma unroll
        for (int n = 0; n < 2; ++n) {
          acc1[m][n] = __builtin_amdgcn_mfma_f32_16x16x32_bf16(a[m], b1[n], acc1[m][n], 0, 0, 0);
          acc2[m][n] = __builtin_amdgcn_mfma_f32_16x16x32_bf16(a[m], b2[n], acc2[m][n], 0, 0, 0);
        }
    }
    __syncthreads();
  }
  int lr = lane & 15, lg = lane >> 4;
  const float* bve = bv + (size_t)e * 2048;
  const float* bge = bg + (size_t)e * 2048;
  #pragma unroll
  for (int m = 0; m < 4; ++m)
    #pragma unroll
    for (int n = 0; n < 2; ++n) {
      int col = n0 + wc*32 + n*16 + lr;
      float bvv = bve[col], bgv = bge[col];
      #pragma unroll
      for (int j = 0; j < 4; ++j) {
        int row = r0 + wr*64 + m*16 + lg*4 + j;
        float v = acc1[m][n][j] + bvv;
        float g = acc2[m][n][j] + bgv;
        float h = v / (1.f + expf(-v)) * g;
        hidden[(size_t)row * 2048 + swzcol(col, row)] = f2bf(h);   // swizzled for gemm2
      }
    }
}

// ---------------- MoE GEMM 2 v7: 128x128 tile, single acc[4][4], XCD-banded ----------------
__global__ __launch_bounds__(256) void moe_gemm2_v7(
    const short* __restrict__ hidden,
    const short* __restrict__ woT,
    const float* __restrict__ bo,
    const int* __restrict__ eoff, const float* __restrict__ wgt,
    short* __restrict__ pout) {
  int rblk, nblk;
  xcd_map<9>(blockIdx.x, rblk, nblk);
  int r0 = rblk * 128;
  if (r0 >= eoff[8]) return;
  int e = 0;
  #pragma unroll
  for (int q = 0; q < 8; ++q) if (r0 >= eoff[q] && r0 < eoff[q+1]) e = q;
  __shared__ short As[128 * 64], Bs[128 * 64];   // 32 KB
  int tid = threadIdx.x, lane = tid & 63, wave = tid >> 6;
  int wr = wave >> 1, wc = wave & 1;
  int n0 = nblk * 128;
  const short* we = woT + (size_t)e * 768 * 2048;
  f32x4 acc[4][4] = {};
  for (int kt = 0; kt < 32; ++kt) {
    stage_tile(hidden, r0, 2048, kt, As, 128, wave, lane);
    stage_tile(we,     n0, 2048, kt, Bs, 128, wave, lane);
    __syncthreads();
    int lr = lane & 15, g4 = lane >> 4;
    #pragma unroll
    for (int ks = 0; ks < 2; ++ks) {
      int slot = ks * 4 + g4;
      short8 a[4];
      #pragma unroll
      for (int m = 0; m < 4; ++m) a[m] = frag(As, wr*64 + m*16 + lr, slot);
      #pragma unroll
      for (int n = 0; n < 4; ++n) {
        short8 b = frag(Bs, wc*64 + n*16 + lr, slot);
        #pragma unroll
        for (int m = 0; m < 4; ++m)
          acc[m][n] = __builtin_amdgcn_mfma_f32_16x16x32_bf16(a[m], b, acc[m][n], 0, 0, 0);
      }
    }
    __syncthreads();
  }
  int lr = lane & 15, lg = lane >> 4;
  const float* boe = bo + (size_t)e * 768;
  #pragma unroll
  for (int m = 0; m < 4; ++m)
    #pragma unroll
    for (int n = 0; n < 4; ++n) {
      int col = n0 + wc*64 + n*16 + lr;
      float bvv = boe[col];
      #pragma unroll
      for (int j = 0; j < 4; ++j) {
        int row = r0 + wr*64 + m*16 + lg*4 + j;
        pout[(size_t)row * 768 + col] = f2bf((acc[m][n][j] + bvv) * wgt[row]);
      }
    }
}

// ---------------- softmax over rows of length 256 ----------------
__global__ __launch_bounds__(256) void softmax256(float* __restrict__ s) {
  int wave = threadIdx.x >> 6, lane = threadIdx.x & 63;
  size_t row = (size_t)blockIdx.x * 4 + wave;
  float* p = s + row * 256;
  float4 v = *(float4*)(p + lane*4);
  float m = fmaxf(fmaxf(v.x, v.y), fmaxf(v.z, v.w));
  #pragma unroll
  for (int off = 32; off; off >>= 1) m = fmaxf(m, __shfl_xor(m, off));
  v.x = expf(v.x - m); v.y = expf(v.y - m); v.z = expf(v.z - m); v.w = expf(v.w - m);
  float sum = v.x + v.y + v.z + v.w;
  #pragma unroll
  for (int off = 32; off; off >>= 1) sum += __shfl_xor(sum, off);
  float r = 1.f / sum;
  v.x *= r; v.y *= r; v.z *= r; v.w *= r;
  *(float4*)(p + lane*4) = v;
}

// ---------------- LayerNorm(xin + add) ----------------
__global__ __launch_bounds__(256) void ln_residual(
    const float* __restrict__ xin, const float* __restrict__ add,
    const float* __restrict__ g, const float* __restrict__ b,
    float* __restrict__ out) {
  int wave = threadIdx.x >> 6, lane = threadIdx.x & 63;
  size_t row = (size_t)blockIdx.x * 4 + wave;
  const float* xp = xin + row * EDIM;
  const float* ap = add + row * EDIM;
  float r[12]; float sum = 0.f, ss = 0.f;
  #pragma unroll
  for (int j = 0; j < 12; ++j) {
    float y = xp[lane + j*64] + ap[lane + j*64];
    r[j] = y; sum += y; ss += y*y;
  }
  #pragma unroll
  for (int off = 32; off; off >>= 1) { sum += __shfl_xor(sum, off); ss += __shfl_xor(ss, off); }
  float mean = sum * (1.f/768.f);
  float var  = ss * (1.f/768.f) - mean*mean;
  float rstd = rsqrtf(var + 1e-5f);
  float* op = out + row * EDIM;
  #pragma unroll
  for (int j = 0; j < 12; ++j) {
    int c = lane + j*64;
    op[c] = (r[j] - mean) * rstd * g[c] + b[c];
  }
}

// ---------------- LayerNorm(xin + add) + write split planes of output ----------------
__global__ __launch_bounds__(256) void ln_residual_split(
    const float* __restrict__ xin, const float* __restrict__ add,
    const float* __restrict__ g, const float* __restrict__ b,
    float* __restrict__ out, short* __restrict__ sp) {
  int wave = threadIdx.x >> 6, lane = threadIdx.x & 63;
  size_t row = (size_t)blockIdx.x * 4 + wave;
  const float* xp = xin + row * EDIM;
  const float* ap = add + row * EDIM;
  float r[12]; float sum = 0.f, ss = 0.f;
  #pragma unroll
  for (int j = 0; j < 12; ++j) {
    float y = xp[lane + j*64] + ap[lane + j*64];
    r[j] = y; sum += y; ss += y*y;
  }
  #pragma unroll
  for (int off = 32; off; off >>= 1) { sum += __shfl_xor(sum, off); ss += __shfl_xor(ss, off); }
  float mean = sum * (1.f/768.f);
  float var  = ss * (1.f/768.f) - mean*mean;
  float rstd = rsqrtf(var + 1e-5f);
  float* op = out + row * EDIM;
  int irow = (int)row;
  #pragma unroll
  for (int j = 0; j < 12; ++j) {
    int c = lane + j*64;
    float y = (r[j] - mean) * rstd * g[c] + b[c];
    op[c] = y;
    short hh, ll; split2(y, hh, ll);
    int d = irow * 768 + swzcol(c, irow);
    sp[d] = hh;
    sp[NTOK * EDIM + d] = ll;
  }
}

// ---------------- final LN: LN(x2 + pout[p0] + pout[p1]) (pout bf16) ----------------
__global__ __launch_bounds__(256) void moe_ln_final(
    const float* __restrict__ x2, const short* __restrict__ pout,
    const int* __restrict__ ppos,
    const float* __restrict__ g, const float* __restrict__ b,
    float* __restrict__ out) {
  int wave = threadIdx.x >> 6, lane = threadIdx.x & 63;
  size_t row = (size_t)blockIdx.x * 4 + wave;
  int p0 = ppos[row*2], p1 = ppos[row*2+1];
  const float* xp = x2 + row * EDIM;
  const short* q0 = pout + (size_t)p0 * EDIM;
  const short* q1 = pout + (size_t)p1 * EDIM;
  float r[12]; float sum = 0.f, ss = 0.f;
  #pragma unroll
  for (int j = 0; j < 12; ++j) {
    int c = lane + j*64;
    float y = xp[c] + bf2f(q0[c]) + bf2f(q1[c]);
    r[j] = y; sum += y; ss += y*y;
  }
  #pragma unroll
  for (int off = 32; off; off >>= 1) { sum += __shfl_xor(sum, off); ss += __shfl_xor(ss, off); }
  float mean = sum * (1.f/768.f);
  float var  = ss * (1.f/768.f) - mean*mean;
  float rstd = rsqrtf(var + 1e-5f);
  float* op = out + row * EDIM;
  #pragma unroll
  for (int j = 0; j < 12; ++j) {
    int c = lane + j*64;
    op[c] = (r[j] - mean) * rstd * g[c] + b[c];
  }
}

// ---------------- temporal attention (T=8 causal), wave per (b,p,h); split-plane output ----------------
__global__ __launch_bounds__(64) void temporal_attn_split(
    const float* __restrict__ q, const float* __restrict__ k,
    const float* __restrict__ v, short* __restrict__ sout) {
  int g = blockIdx.x;
  int b = g / 3072, rem = g % 3072;
  int p = rem / 12, h = rem % 12;
  int lane = threadIdx.x;
  size_t base = (((size_t)b*8)*256 + p) * EDIM + h*64 + lane;
  float qv[8], kv[8], vv[8];
  #pragma unroll
  for (int t = 0; t < 8; ++t) {
    size_t idx = base + (size_t)t * (256*EDIM);
    qv[t] = q[idx]; kv[t] = k[idx]; vv[t] = v[idx];
  }
  float sc[8][8];
  #pragma unroll
  for (int t = 0; t < 8; ++t)
    #pragma unroll
    for (int s2 = 0; s2 < 8; ++s2) {
      if (s2 > t) continue;
      float pr = qv[t] * kv[s2];
      #pragma unroll
      for (int off = 32; off; off >>= 1) pr += __shfl_xor(pr, off);
      sc[t][s2] = pr * 0.125f;
    }
  int c = h * 64 + lane;
  #pragma unroll
  for (int t = 0; t < 8; ++t) {
    float m = sc[t][0];
    #pragma unroll
    for (int s2 = 1; s2 < 8; ++s2) if (s2 <= t) m = fmaxf(m, sc[t][s2]);
    float a[8]; float sum = 0.f;
    #pragma unroll
    for (int s2 = 0; s2 < 8; ++s2) { a[s2] = (s2 <= t) ? expf(sc[t][s2] - m) : 0.f; sum += a[s2]; }
    float r = 1.f / sum;
    float ov = 0.f;
    #pragma unroll
    for (int s2 = 0; s2 < 8; ++s2) ov += a[s2] * vv[s2];
    float y = ov * r;
    int tok = (b * 8 + t) * 256 + p;
    short hh, ll; split2(y, hh, ll);
    int d = tok * 768 + swzcol(c, tok);
    sout[d] = hh;
    sout[NTOK * EDIM + d] = ll;
  }
}

// ---------------- MoE routing (atomic-free, deterministic) ----------------
__global__ void moe_init(int* perm) {
  int i = blockIdx.x*256 + threadIdx.x;
  if (i < MAXR) perm[i] = -1;
}

__global__ __launch_bounds__(256) void router_topk(
    const float* __restrict__ x, const float* __restrict__ rw,
    int* __restrict__ topi, float* __restrict__ topw) {
  int wave = threadIdx.x >> 6, lane = threadIdx.x & 63;
  int tok = blockIdx.x*4 + wave;
  float acc[8] = {0,0,0,0,0,0,0,0};
  const float* xp = x + (size_t)tok * EDIM;
  for (int i = lane; i < EDIM; i += 64) {
    float xv = xp[i];
    const float* w = rw + i*8;
    #pragma unroll
    for (int e = 0; e < 8; ++e) acc[e] += xv * w[e];
  }
  #pragma unroll
  for (int e = 0; e < 8; ++e)
    #pragma unroll
    for (int off = 32; off; off >>= 1) acc[e] += __shfl_xor(acc[e], off);
  if (lane == 0) {
    int i0 = 0; float l0 = acc[0];
    #pragma unroll
    for (int e = 1; e < 8; ++e) if (acc[e] > l0) { l0 = acc[e]; i0 = e; }
    int i1 = -1; float l1 = -3.4e38f;
    #pragma unroll
    for (int e = 0; e < 8; ++e) if (e != i0 && acc[e] > l1) { l1 = acc[e]; i1 = e; }
    float e1 = expf(l1 - l0);
    float w0 = 1.f / (1.f + e1);
    topi[tok*2] = i0; topi[tok*2+1] = i1;
    topw[tok*2] = w0; topw[tok*2+1] = e1 * w0;
  }
}

__global__ __launch_bounds__(256) void moe_count(
    const int* __restrict__ topi, int* __restrict__ cnt) {
  __shared__ int wcnt[4][8];
  int tid = threadIdx.x, lane = tid & 63, wave = tid >> 6;
  int e = topi[blockIdx.x * 256 + tid];
  #pragma unroll
  for (int ee = 0; ee < 8; ++ee) {
    unsigned long long m = __ballot(e == ee);
    if (lane == 0) wcnt[wave][ee] = (int)__popcll(m);
  }
  __syncthreads();
  if (tid < 8)
    cnt[blockIdx.x * 8 + tid] = wcnt[0][tid] + wcnt[1][tid] + wcnt[2][tid] + wcnt[3][tid];
}

__global__ void moe_scan_v2(const int* __restrict__ cnt, int* __restrict__ eoff,
                            int* __restrict__ boff) {
  if (threadIdx.x == 0 && blockIdx.x == 0) {
    int tot[8];
    for (int e = 0; e < 8; ++e) {
      int s = 0;
      for (int b = 0; b < 32; ++b) s += cnt[b*8 + e];
      tot[e] = s;
    }
    int o = 0;
    for (int e = 0; e < 8; ++e) { eoff[e] = o; o += (tot[e] + 127) & ~127; }
    eoff[8] = o;
    for (int e = 0; e < 8; ++e) {
      int r = eoff[e];
      for (int b = 0; b < 32; ++b) { boff[b*8 + e] = r; r += cnt[b*8 + e]; }
    }
  }
}

__global__ __launch_bounds__(256) void moe_fill_v2(
    const int* __restrict__ topi, const float* __restrict__ topw,
    const int* __restrict__ boff,
    int* __restrict__ perm, float* __restrict__ wgt, int* __restrict__ ppos) {
  __shared__ int wcnt[4][8];
  int tid = threadIdx.x, lane = tid & 63, wave = tid >> 6;
  int idx = blockIdx.x * 256 + tid;
  int e = topi[idx];
  unsigned long long mym = 0;
  #pragma unroll
  for (int ee = 0; ee < 8; ++ee) {
    unsigned long long m = __ballot(e == ee);
    if (lane == 0) wcnt[wave][ee] = (int)__popcll(m);
    if (ee == e) mym = m;
  }
  __syncthreads();
  int base = boff[blockIdx.x * 8 + e];
  for (int w = 0; w < wave; ++w) base += wcnt[w][e];
  int pos = base + (int)__popcll(mym & ((1ull << lane) - 1ull));
  perm[pos] = idx >> 1;
  wgt[pos] = topw[idx];
  ppos[idx] = pos;
}

__global__ void moe_gather_bf16(const float* __restrict__ x2, const int* __restrict__ perm,
                                short* __restrict__ Am) {
  int row = blockIdx.x;
  int col = blockIdx.y * 256 + threadIdx.x;
  int t = perm[row];
  short v = (t >= 0) ? f2bf(x2[(size_t)t * 768 + col]) : (short)0;
  Am[(size_t)row * 768 + swzcol(col, row)] = v;
}

// ---------------- host ----------------
extern "C" void kernel_launch(void* const* d_in, const int* in_sizes, int n_in,
                              void* d_out, int out_size, void* d_ws, size_t ws_size,
                              hipStream_t stream) {
  const float* x      = (const float*)d_in[0];
  const float* sa_w[4] = {(const float*)d_in[1], (const float*)d_in[2], (const float*)d_in[3], (const float*)d_in[4]};
  const float* sa_b[4] = {(const float*)d_in[5], (const float*)d_in[6], (const float*)d_in[7], (const float*)d_in[8]};
  const float* sa_g   = (const float*)d_in[9];
  const float* sa_bn  = (const float*)d_in[10];
  const float* ta_w[4] = {(const float*)d_in[11], (const float*)d_in[12], (const float*)d_in[13], (const float*)d_in[14]};
  const float* ta_b[4] = {(const float*)d_in[15], (const float*)d_in[16], (const float*)d_in[17], (const float*)d_in[18]};
  const float* ta_g   = (const float*)d_in[19];
  const float* ta_bn  = (const float*)d_in[20];
  const float* router = (const float*)d_in[21];
  const float* e_wv   = (const float*)d_in[22];
  const float* e_bv   = (const float*)d_in[23];
  const float* e_wg   = (const float*)d_in[24];
  const float* e_bg   = (const float*)d_in[25];
  const float* e_wo   = (const float*)d_in[26];
  const float* e_bo   = (const float*)d_in[27];
  const float* ffn_g  = (const float*)d_in[28];
  const float* ffn_bn = (const float*)d_in[29];

  float* ws    = (float*)d_ws;
  float* q_buf = ws + OFF_Q;
  float* k_buf = ws + OFF_K;
  float* v_buf = ws + OFF_V;
  float* s_buf = ws + OFF_S;
  float* prj   = ws + OFF_PRJ;
  short* asp   = (short*)(ws + OFF_ASPLIT);
  float* x1    = ws + OFF_X1;
  float* x2    = ws + OFF_X2;
  float* vT    = ws + OFF_Q;       // overlays q (dead after QK^T)
  short* wt    = (short*)(ws + OFF_WT);
  // MoE overlay:
  short* hid   = (short*)(ws + OFF_HID);
  short* wvT   = (short*)(ws + OFF_WVT);
  short* wgT   = (short*)(ws + OFF_WGT);
  short* Amoe  = (short*)(ws + OFF_AMOE);
  short* woT   = (short*)(ws + OFF_WOT);
  short* pout  = (short*)(ws + OFF_POUT);
  int*   ip    = (int*)(ws + OFF_INT);
  int* cnt    = ip;                         // 256
  int* eoff   = ip + 256;                   // 16
  int* boff   = ip + 272;                   // 256
  int* topi   = ip + 528;                   // 8192
  int* ppos   = ip + 528 + 8192;            // 8192
  int* perm   = ip + 528 + 16384;           // 9216
  float* topw = (float*)(perm + MAXR);      // 8192
  float* wgt  = topw + 8192;                // 9216

  dim3 blk(256);
  dim3 cgrid(12, 12);
  dim3 cgrid3(12, 12, 3);
  float* out = (float*)d_out;
  const int QKV_LO = 2304 * 768;

  // ======== spatial attention ========
  asplit_kernel<<<1536, blk, 0, stream>>>(x, asp);
  conv_split_T3<<<cgrid3, blk, 0, stream>>>(sa_w[0], sa_w[1], sa_w[2], wt, wt + QKV_LO);
  proj_gemm_v7<4><<<576, blk, 0, stream>>>(
      asp, wt, 2304, sa_b[0], sa_b[1], sa_b[2], q_buf, k_buf, v_buf);
  attn_gemm_split<true, false><<<dim3(4,4,192), blk, 0, stream>>>(
      q_buf, EDIM, 196608, 64, k_buf, EDIM, 196608, 64,
      s_buf, 256, 786432, 65536, 64, 12, 0.125f, nullptr);
  v_transpose<<<dim3(4,192), blk, 0, stream>>>(v_buf, vT);
  softmax256<<<12288, blk, 0, stream>>>(s_buf);
  attn_gemm_split<false, true><<<dim3(4,1,192), blk, 0, stream>>>(
      s_buf, 256, 786432, 65536, vT, 256, 196608, 16384,
      s_buf /*unused*/, EDIM, 196608, 64, 256, 12, 1.f, asp);
  conv_split_T<<<cgrid, blk, 0, stream>>>(sa_w[3], wt, wt + 589824);
  proj_gemm_v7<4><<<192, blk, 0, stream>>>(
      asp, wt, 768, sa_b[3], sa_b[3], sa_b[3], prj, prj, prj);
  ln_residual_split<<<1024, blk, 0, stream>>>(x, prj, sa_g, sa_bn, x1, asp);

  // ======== temporal attention ========
  conv_split_T3<<<cgrid3, blk, 0, stream>>>(ta_w[0], ta_w[1], ta_w[2], wt, wt + QKV_LO);
  proj_gemm_v7<4><<<576, blk, 0, stream>>>(
      asp, wt, 2304, ta_b[0], ta_b[1], ta_b[2], q_buf, k_buf, v_buf);
  temporal_attn_split<<<6144, dim3(64), 0, stream>>>(q_buf, k_buf, v_buf, asp);
  conv_split_T<<<cgrid, blk, 0, stream>>>(ta_w[3], wt, wt + 589824);
  proj_gemm_v7<4><<<192, blk, 0, stream>>>(
      asp, wt, 768, ta_b[3], ta_b[3], ta_b[3], prj, prj, prj);
  ln_residual<<<1024, blk, 0, stream>>>(x1, prj, ta_g, ta_bn, x2);

  // ======== MoE ========
  moe_init<<<(MAXR+255)/256, blk, 0, stream>>>(perm);
  router_topk<<<1024, blk, 0, stream>>>(x2, router, topi, topw);
  moe_count<<<32, blk, 0, stream>>>(topi, cnt);
  moe_scan_v2<<<1, 64, 0, stream>>>(cnt, eoff, boff);
  moe_fill_v2<<<32, blk, 0, stream>>>(topi, topw, boff, perm, wgt, ppos);
  moe_gather_bf16<<<dim3(MAXR,3), blk, 0, stream>>>(x2, perm, Amoe);
  conv_bf16_T<<<dim3(12,32,8), blk, 0, stream>>>(e_wv, wvT, 768, 2048);
  conv_bf16_T<<<dim3(12,32,8), blk, 0, stream>>>(e_wg, wgT, 768, 2048);
  moe_gemm1_v6<<<2304, blk, 0, stream>>>(Amoe, wvT, wgT, e_bv, e_bg, eoff, hid);
  conv_bf16_T<<<dim3(32,12,8), blk, 0, stream>>>(e_wo, woT, 2048, 768);
  moe_gemm2_v7<<<432, blk, 0, stream>>>(hid, woT, e_bo, eoff, wgt, pout);
  moe_ln_final<<<1024, blk, 0, stream>>>(x2, pout, ppos, ffn_g, ffn_bn, out);
}

// Round 14
// 458.629 us; speedup vs baseline: 1.0662x; 1.0662x over previous
//
#include <hip/hip_runtime.h>
#include <hip/hip_bf16.h>

typedef __attribute__((ext_vector_type(8))) short short8;
typedef __attribute__((ext_vector_type(4))) float f32x4;

#define NTOK   4096
#define EDIM   768
#define HFF_   2048
#define MAXR   9216          // 4096*2 pairs + 8*128 alignment pad

// ---- workspace layout (float offsets) ----
#define OFF_Q      0
#define OFF_K      3145728
#define OFF_V      6291456
#define OFF_S      9437184          // s_buf: 12.58M -> ends 22,020,096
#define OFF_PRJ    OFF_S            // prj overlays s region (s dead when prj written)
#define OFF_ASPLIT 22020096         // asp planes -> ends 25,165,824 (no overlap with s_buf)
#define OFF_X1     25165824
#define OFF_X2     28311552
#define OFF_WT     31457280
#define OFF_INT    33226752
// MoE overlay (attention buffers dead):
#define OFF_HID    0
#define OFF_WVT    9437184
#define OFF_WGT    15728640
#define OFF_AMOE   22020096         // overwrites asp only after its last read
#define OFF_WOT    9437184
#define OFF_POUT   15728640

// ---------------- helpers ----------------

__device__ __forceinline__ short f2bf(float f) {
  union { float f; unsigned u; } c; c.f = f;
  unsigned r = (c.u + 0x7fffu + ((c.u >> 16) & 1u)) >> 16;   // RNE
  return (short)r;
}

__device__ __forceinline__ float bf2f(short s) {
  union { unsigned u; float f; } c; c.u = ((unsigned)(unsigned short)s) << 16;
  return c.f;
}

__device__ __forceinline__ void split2(float f, short& h, short& l) {
  short hs = f2bf(f);
  union { unsigned u; float fl; } hv; hv.u = ((unsigned)(unsigned short)hs) << 16;
  h = hs;
  l = f2bf(f - hv.fl);
}

// async 16B/lane global->LDS (dest = uniform base + lane*16)
__device__ __forceinline__ void gload16(const short* g, short* l) {
  __builtin_amdgcn_global_load_lds(
      (const __attribute__((address_space(1))) void*)g,
      (__attribute__((address_space(3))) void*)l, 16, 0, 0);
}

// swizzled column within a 64-short K-chunk: slot' = slot ^ (row&7)
__device__ __forceinline__ int swzcol(int col, int row) {
  return (col & ~63) | ((((col >> 3) & 7) ^ (row & 7)) << 3) | (col & 7);
}

// read one 16B fragment at (row, logical slot) from a linear swizzled LDS tile [R][64]
__device__ __forceinline__ short8 frag(const short* lds, int row, int slot) {
  return *(const short8*)(lds + row * 64 + ((slot ^ (row & 7)) << 3));
}

// stage `rows` rows (chunk kt) of swizzled global matrix P (ld shorts/row) into linear LDS tile
__device__ __forceinline__ void stage_tile(const short* __restrict__ P, long grow0, int ld,
                                           int kt, short* lds, int rows, int wave, int lane) {
  for (int j = wave; j < (rows >> 3); j += 4) {
    const short* src = P + (size_t)(grow0 + j * 8 + (lane >> 3)) * ld + kt * 64 + (lane & 7) * 8;
    gload16(src, lds + (j << 9));
  }
}

// XCD-banded work map: XCD x owns NRP consecutive r-chunks, sweeps n inside.
template<int NRP>
__device__ __forceinline__ void xcd_map(int bid, int& r, int& n) {
  int xcd = bid & 7, sid = bid >> 3;
  n = sid / NRP;
  r = xcd * NRP + (sid - n * NRP);
}

// stage 64(rows) x 32(k) fp32 tile -> hi/lo bf16 LDS [64][40] (attention GEMMs only)
__device__ __forceinline__ void stage_rm2(const float* __restrict__ src, int ld,
                                          short (*hi)[40], short (*lo)[40], int tid) {
  int r = tid >> 2;
  int c = (tid & 3) << 3;
  const float* p = src + (size_t)r * ld + c;
  float4 a = *(const float4*)p;
  float4 b = *(const float4*)(p + 4);
  float f[8] = {a.x, a.y, a.z, a.w, b.x, b.y, b.z, b.w};
  short8 vh, vl;
  #pragma unroll
  for (int j = 0; j < 8; ++j) { short h, l; split2(f[j], h, l); vh[j] = h; vl[j] = l; }
  *(short8*)&hi[r][c] = vh;
  *(short8*)&lo[r][c] = vl;
}

// ---------------- weight split+transpose: w[768][768] -> hi/lo [768 n][768 k], swizzled ----------------
__global__ __launch_bounds__(256) void conv_split_T(
    const float* __restrict__ w, short* __restrict__ hi, short* __restrict__ lo) {
  __shared__ float tile[64][65];
  int tid = threadIdx.x;
  int k0 = blockIdx.x * 64, n0 = blockIdx.y * 64;
  int c = tid & 63, rg = tid >> 6;
  #pragma unroll
  for (int i = 0; i < 16; ++i) {
    int r = rg * 16 + i;
    tile[r][c] = w[(size_t)(k0 + r) * 768 + n0 + c];
  }
  __syncthreads();
  #pragma unroll
  for (int i = 0; i < 16; ++i) {
    int r = rg * 16 + i;
    int n = n0 + r;
    float f = tile[c][r];
    short h, l; split2(f, h, l);
    int cs = ((((c >> 3) ^ (n & 7)) << 3)) | (c & 7);
    hi[(size_t)n * 768 + k0 + cs] = h;
    lo[(size_t)n * 768 + k0 + cs] = l;
  }
}

// fused QKV variant: 3 weights -> one [2304 n][768 k] plane pair
__global__ __launch_bounds__(256) void conv_split_T3(
    const float* __restrict__ w0, const float* __restrict__ w1, const float* __restrict__ w2,
    short* __restrict__ hi, short* __restrict__ lo) {
  __shared__ float tile[64][65];
  const float* w = (blockIdx.z == 0) ? w0 : ((blockIdx.z == 1) ? w1 : w2);
  int nbase = blockIdx.z * 768;
  int tid = threadIdx.x;
  int k0 = blockIdx.x * 64, n0 = blockIdx.y * 64;
  int c = tid & 63, rg = tid >> 6;
  #pragma unroll
  for (int i = 0; i < 16; ++i) {
    int r = rg * 16 + i;
    tile[r][c] = w[(size_t)(k0 + r) * 768 + n0 + c];
  }
  __syncthreads();
  #pragma unroll
  for (int i = 0; i < 16; ++i) {
    int r = rg * 16 + i;
    int n = nbase + n0 + r;
    float f = tile[c][r];
    short h, l; split2(f, h, l);
    int cs = ((((c >> 3) ^ (n & 7)) << 3)) | (c & 7);
    hi[(size_t)n * 768 + k0 + cs] = h;
    lo[(size_t)n * 768 + k0 + cs] = l;
  }
}

// ---------------- transpose-convert: w[z][K][N] fp32 -> o[z][N][K] bf16, swizzled ----------------
__global__ __launch_bounds__(256) void conv_bf16_T(
    const float* __restrict__ w, short* __restrict__ o, int K, int N) {
  __shared__ float tile[64][65];
  int tid = threadIdx.x;
  int z = blockIdx.z;
  const float* wz = w + (size_t)z * K * N;
  short* oz = o + (size_t)z * K * N;
  int k0 = blockIdx.x * 64, n0 = blockIdx.y * 64;
  int c = tid & 63, rg = tid >> 6;
  #pragma unroll
  for (int i = 0; i < 16; ++i) {
    int r = rg * 16 + i;
    tile[r][c] = wz[(size_t)(k0 + r) * N + n0 + c];
  }
  __syncthreads();
  #pragma unroll
  for (int i = 0; i < 16; ++i) {
    int r = rg * 16 + i;
    int n = n0 + r;
    int cs = ((((c >> 3) ^ (n & 7)) << 3)) | (c & 7);
    oz[(size_t)n * K + k0 + cs] = f2bf(tile[c][r]);
  }
}

// ---------------- activation split: fp32 -> hi/lo bf16 planes, swizzled ----------------
__global__ __launch_bounds__(256) void asplit_kernel(
    const float* __restrict__ a, short* __restrict__ hi) {
  int i = (blockIdx.x * 256 + threadIdx.x) * 8;
  int row = i / 768, cc = i % 768;
  float4 f0 = *(const float4*)(a + i);
  float4 f1 = *(const float4*)(a + i + 4);
  float f[8] = {f0.x, f0.y, f0.z, f0.w, f1.x, f1.y, f1.z, f1.w};
  short8 h, l;
  #pragma unroll
  for (int j = 0; j < 8; ++j) { short hh, ll; split2(f[j], hh, ll); h[j] = hh; l[j] = ll; }
  int d = row * 768 + swzcol(cc, row);
  *(short8*)(hi + d) = h;
  *(short8*)(hi + NTOK * EDIM + d) = l;
}

// ---------------- projection GEMM v6: 128x64 tile, acc[4][2] (32 AGPR), XCD-banded ----------------
template<int NRP>
__global__ __launch_bounds__(256) void proj_gemm_v6(
    const short* __restrict__ Asp, const short* __restrict__ wt, int wtotal,
    const float* __restrict__ b0, const float* __restrict__ b1, const float* __restrict__ b2,
    float* __restrict__ C0, float* __restrict__ C1, float* __restrict__ C2) {
  __shared__ short Ah[128 * 64], Al[128 * 64], Bh[64 * 64], Bl[64 * 64];
  int tid = threadIdx.x, lane = tid & 63, wave = tid >> 6;
  int wr = wave >> 1, wc = wave & 1;
  int rblk, nblk;
  xcd_map<NRP>(blockIdx.x, rblk, nblk);
  int row0 = rblk * 128, col0 = nblk * 64;
  const short* alo = Asp + NTOK * EDIM;
  const short* wlo = wt + (size_t)wtotal * 768;
  f32x4 acc[4][2] = {};
  for (int kt = 0; kt < 12; ++kt) {
    stage_tile(Asp, row0, 768, kt, Ah, 128, wave, lane);
    stage_tile(alo, row0, 768, kt, Al, 128, wave, lane);
    stage_tile(wt,  col0, 768, kt, Bh, 64,  wave, lane);
    stage_tile(wlo, col0, 768, kt, Bl, 64,  wave, lane);
    __syncthreads();
    int lr = lane & 15, g4 = lane >> 4;
    #pragma unroll
    for (int ks = 0; ks < 2; ++ks) {
      int slot = ks * 4 + g4;
      short8 ah[4], al[4], bh[2], bl[2];
      #pragma unroll
      for (int m = 0; m < 4; ++m) {
        int row = wr * 64 + m * 16 + lr;
        ah[m] = frag(Ah, row, slot);
        al[m] = frag(Al, row, slot);
      }
      #pragma unroll
      for (int n = 0; n < 2; ++n) {
        int row = wc * 32 + n * 16 + lr;
        bh[n] = frag(Bh, row, slot);
        bl[n] = frag(Bl, row, slot);
      }
      #pragma unroll
      for (int m = 0; m < 4; ++m)
        #pragma unroll
        for (int n = 0; n < 2; ++n) {
          acc[m][n] = __builtin_amdgcn_mfma_f32_16x16x32_bf16(ah[m], bh[n], acc[m][n], 0, 0, 0);
          acc[m][n] = __builtin_amdgcn_mfma_f32_16x16x32_bf16(ah[m], bl[n], acc[m][n], 0, 0, 0);
          acc[m][n] = __builtin_amdgcn_mfma_f32_16x16x32_bf16(al[m], bh[n], acc[m][n], 0, 0, 0);
        }
    }
    __syncthreads();
  }
  int seg = col0 / 768;
  const float* bp = (seg == 0) ? b0 : ((seg == 1) ? b1 : b2);
  float*       Cd = (seg == 0) ? C0 : ((seg == 1) ? C1 : C2);
  int cb = col0 - seg * 768;
  int lr = lane & 15, lg = lane >> 4;
  #pragma unroll
  for (int m = 0; m < 4; ++m)
    #pragma unroll
    for (int n = 0; n < 2; ++n) {
      int ccol = cb + wc * 32 + n * 16 + lr;
      float bv = bp[ccol];
      #pragma unroll
      for (int j = 0; j < 4; ++j) {
        int row = row0 + wr * 64 + m * 16 + lg * 4 + j;
        Cd[(size_t)row * 768 + ccol] = acc[m][n][j] + bv;
      }
    }
}

// ---------------- V transpose: v[bt][p][768] -> vT[bt*12+h][64][256] ----------------
__global__ __launch_bounds__(256) void v_transpose(
    const float* __restrict__ v, float* __restrict__ vT) {
  __shared__ float tile[64][65];
  int tid = threadIdx.x;
  int z = blockIdx.y;
  int bt = z / 12, h = z % 12;
  int p0 = blockIdx.x * 64;
  int c = tid & 63, rg = tid >> 6;
  #pragma unroll
  for (int i = 0; i < 16; ++i) {
    int r = rg * 16 + i;
    tile[r][c] = v[((size_t)bt * 256 + p0 + r) * 768 + h * 64 + c];
  }
  __syncthreads();
  #pragma unroll
  for (int i = 0; i < 16; ++i) {
    int r = rg * 16 + i;
    vT[((size_t)z * 64 + r) * 256 + p0 + c] = tile[c][r];
  }
}

// ---------------- attention GEMM (split, B^T); SPLITOUT writes hi/lo planes for AV ----------------
template<bool HAS_ALPHA, bool SPLITOUT>
__global__ __launch_bounds__(256) void attn_gemm_split(
    const float* __restrict__ A, int lda, long sA1, long sA2,
    const float* __restrict__ B, int ldb, long sB1, long sB2,
    float* __restrict__ C, int ldc, long sC1, long sC2,
    int K, int nz2, float alpha, short* __restrict__ sout) {
  __shared__ short Ah[64][40], Al[64][40], Bh[64][40], Bl[64][40];
  int tid = threadIdx.x;
  int lane = tid & 63, wave = tid >> 6;
  int wr = wave >> 1, wc = wave & 1;
  int z = blockIdx.z, z1 = z / nz2, z2 = z % nz2;
  const float* Ab = A + z1*sA1 + z2*sA2 + (size_t)blockIdx.x * 64 * lda;
  const float* Bb = B + z1*sB1 + z2*sB2 + (size_t)blockIdx.y * 64 * ldb;
  float* Cb = C + z1*sC1 + z2*sC2;
  f32x4 acc[2][2] = {};
  int nk = K >> 5;
  for (int kt = 0; kt < nk; ++kt) {
    stage_rm2(Ab + kt*32, lda, Ah, Al, tid);
    stage_rm2(Bb + kt*32, ldb, Bh, Bl, tid);
    __syncthreads();
    int lr = lane & 15, lk = (lane >> 4) * 8;
    short8 ah[2], al[2], bh[2], bl[2];
    #pragma unroll
    for (int m = 0; m < 2; ++m) {
      ah[m] = *(const short8*)&Ah[wr*32 + m*16 + lr][lk];
      al[m] = *(const short8*)&Al[wr*32 + m*16 + lr][lk];
    }
    #pragma unroll
    for (int n = 0; n < 2; ++n) {
      bh[n] = *(const short8*)&Bh[wc*32 + n*16 + lr][lk];
      bl[n] = *(const short8*)&Bl[wc*32 + n*16 + lr][lk];
    }
    #pragma unroll
    for (int m = 0; m < 2; ++m)
      #pragma unroll
      for (int n = 0; n < 2; ++n) {
        acc[m][n] = __builtin_amdgcn_mfma_f32_16x16x32_bf16(ah[m], bh[n], acc[m][n], 0, 0, 0);
        acc[m][n] = __builtin_amdgcn_mfma_f32_16x16x32_bf16(ah[m], bl[n], acc[m][n], 0, 0, 0);
        acc[m][n] = __builtin_amdgcn_mfma_f32_16x16x32_bf16(al[m], bh[n], acc[m][n], 0, 0, 0);
      }
    __syncthreads();
  }
  int lr = lane & 15, lg = lane >> 4;
  int row0 = blockIdx.x*64 + wr*32;
  int col0 = blockIdx.y*64 + wc*32;
  #pragma unroll
  for (int m = 0; m < 2; ++m)
    #pragma unroll
    for (int n = 0; n < 2; ++n) {
      int col = col0 + n*16 + lr;
      #pragma unroll
      for (int j = 0; j < 4; ++j) {
        int row = row0 + m*16 + lg*4 + j;
        float v = HAS_ALPHA ? acc[m][n][j]*alpha : acc[m][n][j];
        if (SPLITOUT) {
          // AV: z1 = bt (0..15), z2 = head; token = z1*256+row, channel = z2*64+col
          int tok = z1 * 256 + row;
          int c = z2 * 64 + col;
          short hh, ll; split2(v, hh, ll);
          int d = tok * 768 + swzcol(c, tok);
          sout[d] = hh;
          sout[NTOK * EDIM + d] = ll;
        } else {
          Cb[(size_t)row*ldc + col] = v;
        }
      }
    }
}

// ---------------- MoE GEMM 1: 128x64 tile, dual acc, XCD-banded ----------------
__global__ __launch_bounds__(256) void moe_gemm1_v6(
    const short* __restrict__ Am,
    const short* __restrict__ wvT, const short* __restrict__ wgT,
    const float* __restrict__ bv, const float* __restrict__ bg,
    const int* __restrict__ eoff, short* __restrict__ hidden) {
  int rblk, nblk;
  xcd_map<9>(blockIdx.x, rblk, nblk);
  int r0 = rblk * 128;
  if (r0 >= eoff[8]) return;
  int e = 0;
  #pragma unroll
  for (int q = 0; q < 8; ++q) if (r0 >= eoff[q] && r0 < eoff[q+1]) e = q;
  __shared__ short As[128 * 64], B1[64 * 64], B2[64 * 64];
  int tid = threadIdx.x, lane = tid & 63, wave = tid >> 6;
  int wr = wave >> 1, wc = wave & 1;
  int n0 = nblk * 64;
  const short* w1 = wvT + (size_t)e * 2048 * 768;
  const short* w2 = wgT + (size_t)e * 2048 * 768;
  f32x4 acc1[4][2] = {}, acc2[4][2] = {};
  for (int kt = 0; kt < 12; ++kt) {
    stage_tile(Am, r0, 768, kt, As, 128, wave, lane);
    stage_tile(w1, n0, 768, kt, B1, 64, wave, lane);
    stage_tile(w2, n0, 768, kt, B2, 64, wave, lane);
    __syncthreads();
    int lr = lane & 15, g4 = lane >> 4;
    #pragma unroll
    for (int ks = 0; ks < 2; ++ks) {
      int slot = ks * 4 + g4;
      short8 a[4], b1[2], b2[2];
      #pragma unroll
      for (int m = 0; m < 4; ++m) a[m] = frag(As, wr*64 + m*16 + lr, slot);
      #pragma unroll
      for (int n = 0; n < 2; ++n) {
        int row = wc*32 + n*16 + lr;
        b1[n] = frag(B1, row, slot);
        b2[n] = frag(B2, row, slot);
      }
      #pragma unroll
      for (int m = 0; m < 4; ++m)
        #pragma unroll
        for (int n = 0; n < 2; ++n) {
          acc1[m][n] = __builtin_amdgcn_mfma_f32_16x16x32_bf16(a[m], b1[n], acc1[m][n], 0, 0, 0);
          acc2[m][n] = __builtin_amdgcn_mfma_f32_16x16x32_bf16(a[m], b2[n], acc2[m][n], 0, 0, 0);
        }
    }
    __syncthreads();
  }
  int lr = lane & 15, lg = lane >> 4;
  const float* bve = bv + (size_t)e * 2048;
  const float* bge = bg + (size_t)e * 2048;
  #pragma unroll
  for (int m = 0; m < 4; ++m)
    #pragma unroll
    for (int n = 0; n < 2; ++n) {
      int col = n0 + wc*32 + n*16 + lr;
      float bvv = bve[col], bgv = bge[col];
      #pragma unroll
      for (int j = 0; j < 4; ++j) {
        int row = r0 + wr*64 + m*16 + lg*4 + j;
        float v = acc1[m][n][j] + bvv;
        float g = acc2[m][n][j] + bgv;
        float h = v / (1.f + expf(-v)) * g;
        hidden[(size_t)row * 2048 + swzcol(col, row)] = f2bf(h);   // swizzled for gemm2
      }
    }
}

// ---------------- MoE GEMM 2: 128x64 tile, XCD-banded ----------------
__global__ __launch_bounds__(256) void moe_gemm2_v6(
    const short* __restrict__ hidden,
    const short* __restrict__ woT,
    const float* __restrict__ bo,
    const int* __restrict__ eoff, const float* __restrict__ wgt,
    short* __restrict__ pout) {
  int rblk, nblk;
  xcd_map<9>(blockIdx.x, rblk, nblk);
  int r0 = rblk * 128;
  if (r0 >= eoff[8]) return;
  int e = 0;
  #pragma unroll
  for (int q = 0; q < 8; ++q) if (r0 >= eoff[q] && r0 < eoff[q+1]) e = q;
  __shared__ short As[128 * 64], Bs[64 * 64];
  int tid = threadIdx.x, lane = tid & 63, wave = tid >> 6;
  int wr = wave >> 1, wc = wave & 1;
  int n0 = nblk * 64;
  const short* we = woT + (size_t)e * 768 * 2048;
  f32x4 acc[4][2] = {};
  for (int kt = 0; kt < 32; ++kt) {
    stage_tile(hidden, r0, 2048, kt, As, 128, wave, lane);
    stage_tile(we,     n0, 2048, kt, Bs, 64, wave, lane);
    __syncthreads();
    int lr = lane & 15, g4 = lane >> 4;
    #pragma unroll
    for (int ks = 0; ks < 2; ++ks) {
      int slot = ks * 4 + g4;
      short8 a[4], b[2];
      #pragma unroll
      for (int m = 0; m < 4; ++m) a[m] = frag(As, wr*64 + m*16 + lr, slot);
      #pragma unroll
      for (int n = 0; n < 2; ++n) b[n] = frag(Bs, wc*32 + n*16 + lr, slot);
      #pragma unroll
      for (int m = 0; m < 4; ++m)
        #pragma unroll
        for (int n = 0; n < 2; ++n)
          acc[m][n] = __builtin_amdgcn_mfma_f32_16x16x32_bf16(a[m], b[n], acc[m][n], 0, 0, 0);
    }
    __syncthreads();
  }
  int lr = lane & 15, lg = lane >> 4;
  const float* boe = bo + (size_t)e * 768;
  #pragma unroll
  for (int m = 0; m < 4; ++m)
    #pragma unroll
    for (int n = 0; n < 2; ++n) {
      int col = n0 + wc*32 + n*16 + lr;
      float bvv = boe[col];
      #pragma unroll
      for (int j = 0; j < 4; ++j) {
        int row = r0 + wr*64 + m*16 + lg*4 + j;
        pout[(size_t)row * 768 + col] = f2bf((acc[m][n][j] + bvv) * wgt[row]);
      }
    }
}

// ---------------- softmax over rows of length 256 ----------------
__global__ __launch_bounds__(256) void softmax256(float* __restrict__ s) {
  int wave = threadIdx.x >> 6, lane = threadIdx.x & 63;
  size_t row = (size_t)blockIdx.x * 4 + wave;
  float* p = s + row * 256;
  float4 v = *(float4*)(p + lane*4);
  float m = fmaxf(fmaxf(v.x, v.y), fmaxf(v.z, v.w));
  #pragma unroll
  for (int off = 32; off; off >>= 1) m = fmaxf(m, __shfl_xor(m, off));
  v.x = expf(v.x - m); v.y = expf(v.y - m); v.z = expf(v.z - m); v.w = expf(v.w - m);
  float sum = v.x + v.y + v.z + v.w;
  #pragma unroll
  for (int off = 32; off; off >>= 1) sum += __shfl_xor(sum, off);
  float r = 1.f / sum;
  v.x *= r; v.y *= r; v.z *= r; v.w *= r;
  *(float4*)(p + lane*4) = v;
}

// ---------------- LayerNorm(xin + add) ----------------
__global__ __launch_bounds__(256) void ln_residual(
    const float* __restrict__ xin, const float* __restrict__ add,
    const float* __restrict__ g, const float* __restrict__ b,
    float* __restrict__ out) {
  int wave = threadIdx.x >> 6, lane = threadIdx.x & 63;
  size_t row = (size_t)blockIdx.x * 4 + wave;
  const float* xp = xin + row * EDIM;
  const float* ap = add + row * EDIM;
  float r[12]; float sum = 0.f, ss = 0.f;
  #pragma unroll
  for (int j = 0; j < 12; ++j) {
    float y = xp[lane + j*64] + ap[lane + j*64];
    r[j] = y; sum += y; ss += y*y;
  }
  #pragma unroll
  for (int off = 32; off; off >>= 1) { sum += __shfl_xor(sum, off); ss += __shfl_xor(ss, off); }
  float mean = sum * (1.f/768.f);
  float var  = ss * (1.f/768.f) - mean*mean;
  float rstd = rsqrtf(var + 1e-5f);
  float* op = out + row * EDIM;
  #pragma unroll
  for (int j = 0; j < 12; ++j) {
    int c = lane + j*64;
    op[c] = (r[j] - mean) * rstd * g[c] + b[c];
  }
}

// ---------------- LayerNorm(xin + add) + write split planes of output ----------------
__global__ __launch_bounds__(256) void ln_residual_split(
    const float* __restrict__ xin, const float* __restrict__ add,
    const float* __restrict__ g, const float* __restrict__ b,
    float* __restrict__ out, short* __restrict__ sp) {
  int wave = threadIdx.x >> 6, lane = threadIdx.x & 63;
  size_t row = (size_t)blockIdx.x * 4 + wave;
  const float* xp = xin + row * EDIM;
  const float* ap = add + row * EDIM;
  float r[12]; float sum = 0.f, ss = 0.f;
  #pragma unroll
  for (int j = 0; j < 12; ++j) {
    float y = xp[lane + j*64] + ap[lane + j*64];
    r[j] = y; sum += y; ss += y*y;
  }
  #pragma unroll
  for (int off = 32; off; off >>= 1) { sum += __shfl_xor(sum, off); ss += __shfl_xor(ss, off); }
  float mean = sum * (1.f/768.f);
  float var  = ss * (1.f/768.f) - mean*mean;
  float rstd = rsqrtf(var + 1e-5f);
  float* op = out + row * EDIM;
  int irow = (int)row;
  #pragma unroll
  for (int j = 0; j < 12; ++j) {
    int c = lane + j*64;
    float y = (r[j] - mean) * rstd * g[c] + b[c];
    op[c] = y;
    short hh, ll; split2(y, hh, ll);
    int d = irow * 768 + swzcol(c, irow);
    sp[d] = hh;
    sp[NTOK * EDIM + d] = ll;
  }
}

// ---------------- final LN: LN(x2 + pout[p0] + pout[p1]) (pout bf16) ----------------
__global__ __launch_bounds__(256) void moe_ln_final(
    const float* __restrict__ x2, const short* __restrict__ pout,
    const int* __restrict__ ppos,
    const float* __restrict__ g, const float* __restrict__ b,
    float* __restrict__ out) {
  int wave = threadIdx.x >> 6, lane = threadIdx.x & 63;
  size_t row = (size_t)blockIdx.x * 4 + wave;
  int p0 = ppos[row*2], p1 = ppos[row*2+1];
  const float* xp = x2 + row * EDIM;
  const short* q0 = pout + (size_t)p0 * EDIM;
  const short* q1 = pout + (size_t)p1 * EDIM;
  float r[12]; float sum = 0.f, ss = 0.f;
  #pragma unroll
  for (int j = 0; j < 12; ++j) {
    int c = lane + j*64;
    float y = xp[c] + bf2f(q0[c]) + bf2f(q1[c]);
    r[j] = y; sum += y; ss += y*y;
  }
  #pragma unroll
  for (int off = 32; off; off >>= 1) { sum += __shfl_xor(sum, off); ss += __shfl_xor(ss, off); }
  float mean = sum * (1.f/768.f);
  float var  = ss * (1.f/768.f) - mean*mean;
  float rstd = rsqrtf(var + 1e-5f);
  float* op = out + row * EDIM;
  #pragma unroll
  for (int j = 0; j < 12; ++j) {
    int c = lane + j*64;
    op[c] = (r[j] - mean) * rstd * g[c] + b[c];
  }
}

// ---------------- temporal attention (T=8 causal), wave per (b,p,h); split-plane output ----------------
__global__ __launch_bounds__(64) void temporal_attn_split(
    const float* __restrict__ q, const float* __restrict__ k,
    const float* __restrict__ v, short* __restrict__ sout) {
  int g = blockIdx.x;
  int b = g / 3072, rem = g % 3072;
  int p = rem / 12, h = rem % 12;
  int lane = threadIdx.x;
  size_t base = (((size_t)b*8)*256 + p) * EDIM + h*64 + lane;
  float qv[8], kv[8], vv[8];
  #pragma unroll
  for (int t = 0; t < 8; ++t) {
    size_t idx = base + (size_t)t * (256*EDIM);
    qv[t] = q[idx]; kv[t] = k[idx]; vv[t] = v[idx];
  }
  float sc[8][8];
  #pragma unroll
  for (int t = 0; t < 8; ++t)
    #pragma unroll
    for (int s2 = 0; s2 < 8; ++s2) {
      if (s2 > t) continue;
      float pr = qv[t] * kv[s2];
      #pragma unroll
      for (int off = 32; off; off >>= 1) pr += __shfl_xor(pr, off);
      sc[t][s2] = pr * 0.125f;
    }
  int c = h * 64 + lane;
  #pragma unroll
  for (int t = 0; t < 8; ++t) {
    float m = sc[t][0];
    #pragma unroll
    for (int s2 = 1; s2 < 8; ++s2) if (s2 <= t) m = fmaxf(m, sc[t][s2]);
    float a[8]; float sum = 0.f;
    #pragma unroll
    for (int s2 = 0; s2 < 8; ++s2) { a[s2] = (s2 <= t) ? expf(sc[t][s2] - m) : 0.f; sum += a[s2]; }
    float r = 1.f / sum;
    float ov = 0.f;
    #pragma unroll
    for (int s2 = 0; s2 < 8; ++s2) ov += a[s2] * vv[s2];
    float y = ov * r;
    int tok = (b * 8 + t) * 256 + p;
    short hh, ll; split2(y, hh, ll);
    int d = tok * 768 + swzcol(c, tok);
    sout[d] = hh;
    sout[NTOK * EDIM + d] = ll;
  }
}

// ---------------- MoE routing (atomic-free, deterministic) ----------------
__global__ void moe_init(int* perm) {
  int i = blockIdx.x*256 + threadIdx.x;
  if (i < MAXR) perm[i] = -1;
}

__global__ __launch_bounds__(256) void router_topk(
    const float* __restrict__ x, const float* __restrict__ rw,
    int* __restrict__ topi, float* __restrict__ topw) {
  int wave = threadIdx.x >> 6, lane = threadIdx.x & 63;
  int tok = blockIdx.x*4 + wave;
  float acc[8] = {0,0,0,0,0,0,0,0};
  const float* xp = x + (size_t)tok * EDIM;
  for (int i = lane; i < EDIM; i += 64) {
    float xv = xp[i];
    const float* w = rw + i*8;
    #pragma unroll
    for (int e = 0; e < 8; ++e) acc[e] += xv * w[e];
  }
  #pragma unroll
  for (int e = 0; e < 8; ++e)
    #pragma unroll
    for (int off = 32; off; off >>= 1) acc[e] += __shfl_xor(acc[e], off);
  if (lane == 0) {
    int i0 = 0; float l0 = acc[0];
    #pragma unroll
    for (int e = 1; e < 8; ++e) if (acc[e] > l0) { l0 = acc[e]; i0 = e; }
    int i1 = -1; float l1 = -3.4e38f;
    #pragma unroll
    for (int e = 0; e < 8; ++e) if (e != i0 && acc[e] > l1) { l1 = acc[e]; i1 = e; }
    float e1 = expf(l1 - l0);
    float w0 = 1.f / (1.f + e1);
    topi[tok*2] = i0; topi[tok*2+1] = i1;
    topw[tok*2] = w0; topw[tok*2+1] = e1 * w0;
  }
}

__global__ __launch_bounds__(256) void moe_count(
    const int* __restrict__ topi, int* __restrict__ cnt) {
  __shared__ int wcnt[4][8];
  int tid = threadIdx.x, lane = tid & 63, wave = tid >> 6;
  int e = topi[blockIdx.x * 256 + tid];
  #pragma unroll
  for (int ee = 0; ee < 8; ++ee) {
    unsigned long long m = __ballot(e == ee);
    if (lane == 0) wcnt[wave][ee] = (int)__popcll(m);
  }
  __syncthreads();
  if (tid < 8)
    cnt[blockIdx.x * 8 + tid] = wcnt[0][tid] + wcnt[1][tid] + wcnt[2][tid] + wcnt[3][tid];
}

__global__ void moe_scan_v2(const int* __restrict__ cnt, int* __restrict__ eoff,
                            int* __restrict__ boff) {
  if (threadIdx.x == 0 && blockIdx.x == 0) {
    int tot[8];
    for (int e = 0; e < 8; ++e) {
      int s = 0;
      for (int b = 0; b < 32; ++b) s += cnt[b*8 + e];
      tot[e] = s;
    }
    int o = 0;
    for (int e = 0; e < 8; ++e) { eoff[e] = o; o += (tot[e] + 127) & ~127; }
    eoff[8] = o;
    for (int e = 0; e < 8; ++e) {
      int r = eoff[e];
      for (int b = 0; b < 32; ++b) { boff[b*8 + e] = r; r += cnt[b*8 + e]; }
    }
  }
}

__global__ __launch_bounds__(256) void moe_fill_v2(
    const int* __restrict__ topi, const float* __restrict__ topw,
    const int* __restrict__ boff,
    int* __restrict__ perm, float* __restrict__ wgt, int* __restrict__ ppos) {
  __shared__ int wcnt[4][8];
  int tid = threadIdx.x, lane = tid & 63, wave = tid >> 6;
  int idx = blockIdx.x * 256 + tid;
  int e = topi[idx];
  unsigned long long mym = 0;
  #pragma unroll
  for (int ee = 0; ee < 8; ++ee) {
    unsigned long long m = __ballot(e == ee);
    if (lane == 0) wcnt[wave][ee] = (int)__popcll(m);
    if (ee == e) mym = m;
  }
  __syncthreads();
  int base = boff[blockIdx.x * 8 + e];
  for (int w = 0; w < wave; ++w) base += wcnt[w][e];
  int pos = base + (int)__popcll(mym & ((1ull << lane) - 1ull));
  perm[pos] = idx >> 1;
  wgt[pos] = topw[idx];
  ppos[idx] = pos;
}

__global__ void moe_gather_bf16(const float* __restrict__ x2, const int* __restrict__ perm,
                                short* __restrict__ Am) {
  int row = blockIdx.x;
  int col = blockIdx.y * 256 + threadIdx.x;
  int t = perm[row];
  short v = (t >= 0) ? f2bf(x2[(size_t)t * 768 + col]) : (short)0;
  Am[(size_t)row * 768 + swzcol(col, row)] = v;
}

// ---------------- host ----------------
extern "C" void kernel_launch(void* const* d_in, const int* in_sizes, int n_in,
                              void* d_out, int out_size, void* d_ws, size_t ws_size,
                              hipStream_t stream) {
  const float* x      = (const float*)d_in[0];
  const float* sa_w[4] = {(const float*)d_in[1], (const float*)d_in[2], (const float*)d_in[3], (const float*)d_in[4]};
  const float* sa_b[4] = {(const float*)d_in[5], (const float*)d_in[6], (const float*)d_in[7], (const float*)d_in[8]};
  const float* sa_g   = (const float*)d_in[9];
  const float* sa_bn  = (const float*)d_in[10];
  const float* ta_w[4] = {(const float*)d_in[11], (const float*)d_in[12], (const float*)d_in[13], (const float*)d_in[14]};
  const float* ta_b[4] = {(const float*)d_in[15], (const float*)d_in[16], (const float*)d_in[17], (const float*)d_in[18]};
  const float* ta_g   = (const float*)d_in[19];
  const float* ta_bn  = (const float*)d_in[20];
  const float* router = (const float*)d_in[21];
  const float* e_wv   = (const float*)d_in[22];
  const float* e_bv   = (const float*)d_in[23];
  const float* e_wg   = (const float*)d_in[24];
  const float* e_bg   = (const float*)d_in[25];
  const float* e_wo   = (const float*)d_in[26];
  const float* e_bo   = (const float*)d_in[27];
  const float* ffn_g  = (const float*)d_in[28];
  const float* ffn_bn = (const float*)d_in[29];

  float* ws    = (float*)d_ws;
  float* q_buf = ws + OFF_Q;
  float* k_buf = ws + OFF_K;
  float* v_buf = ws + OFF_V;
  float* s_buf = ws + OFF_S;
  float* prj   = ws + OFF_PRJ;
  short* asp   = (short*)(ws + OFF_ASPLIT);
  float* x1    = ws + OFF_X1;
  float* x2    = ws + OFF_X2;
  float* vT    = ws + OFF_Q;       // overlays q (dead after QK^T)
  short* wt    = (short*)(ws + OFF_WT);
  // MoE overlay:
  short* hid   = (short*)(ws + OFF_HID);
  short* wvT   = (short*)(ws + OFF_WVT);
  short* wgT   = (short*)(ws + OFF_WGT);
  short* Amoe  = (short*)(ws + OFF_AMOE);
  short* woT   = (short*)(ws + OFF_WOT);
  short* pout  = (short*)(ws + OFF_POUT);
  int*   ip    = (int*)(ws + OFF_INT);
  int* cnt    = ip;                         // 256
  int* eoff   = ip + 256;                   // 16
  int* boff   = ip + 272;                   // 256
  int* topi   = ip + 528;                   // 8192
  int* ppos   = ip + 528 + 8192;            // 8192
  int* perm   = ip + 528 + 16384;           // 9216
  float* topw = (float*)(perm + MAXR);      // 8192
  float* wgt  = topw + 8192;                // 9216

  dim3 blk(256);
  dim3 cgrid(12, 12);
  dim3 cgrid3(12, 12, 3);
  float* out = (float*)d_out;
  const int QKV_LO = 2304 * 768;

  // ======== spatial attention ========
  asplit_kernel<<<1536, blk, 0, stream>>>(x, asp);
  conv_split_T3<<<cgrid3, blk, 0, stream>>>(sa_w[0], sa_w[1], sa_w[2], wt, wt + QKV_LO);
  proj_gemm_v6<4><<<1152, blk, 0, stream>>>(
      asp, wt, 2304, sa_b[0], sa_b[1], sa_b[2], q_buf, k_buf, v_buf);
  attn_gemm_split<true, false><<<dim3(4,4,192), blk, 0, stream>>>(
      q_buf, EDIM, 196608, 64, k_buf, EDIM, 196608, 64,
      s_buf, 256, 786432, 65536, 64, 12, 0.125f, nullptr);
  v_transpose<<<dim3(4,192), blk, 0, stream>>>(v_buf, vT);
  softmax256<<<12288, blk, 0, stream>>>(s_buf);
  // AV: writes split planes of o directly (asp does not overlap s_buf)
  attn_gemm_split<false, true><<<dim3(4,1,192), blk, 0, stream>>>(
      s_buf, 256, 786432, 65536, vT, 256, 196608, 16384,
      s_buf /*unused*/, EDIM, 196608, 64, 256, 12, 1.f, asp);
  conv_split_T<<<cgrid, blk, 0, stream>>>(sa_w[3], wt, wt + 589824);
  proj_gemm_v6<4><<<384, blk, 0, stream>>>(
      asp, wt, 768, sa_b[3], sa_b[3], sa_b[3], prj, prj, prj);
  ln_residual_split<<<1024, blk, 0, stream>>>(x, prj, sa_g, sa_bn, x1, asp);

  // ======== temporal attention ========
  conv_split_T3<<<cgrid3, blk, 0, stream>>>(ta_w[0], ta_w[1], ta_w[2], wt, wt + QKV_LO);
  proj_gemm_v6<4><<<1152, blk, 0, stream>>>(
      asp, wt, 2304, ta_b[0], ta_b[1], ta_b[2], q_buf, k_buf, v_buf);
  temporal_attn_split<<<6144, dim3(64), 0, stream>>>(q_buf, k_buf, v_buf, asp);
  conv_split_T<<<cgrid, blk, 0, stream>>>(ta_w[3], wt, wt + 589824);
  proj_gemm_v6<4><<<384, blk, 0, stream>>>(
      asp, wt, 768, ta_b[3], ta_b[3], ta_b[3], prj, prj, prj);
  ln_residual<<<1024, blk, 0, stream>>>(x1, prj, ta_g, ta_bn, x2);

  // ======== MoE ========
  moe_init<<<(MAXR+255)/256, blk, 0, stream>>>(perm);
  router_topk<<<1024, blk, 0, stream>>>(x2, router, topi, topw);
  moe_count<<<32, blk, 0, stream>>>(topi, cnt);
  moe_scan_v2<<<1, 64, 0, stream>>>(cnt, eoff, boff);
  moe_fill_v2<<<32, blk, 0, stream>>>(topi, topw, boff, perm, wgt, ppos);
  moe_gather_bf16<<<dim3(MAXR,3), blk, 0, stream>>>(x2, perm, Amoe);
  conv_bf16_T<<<dim3(12,32,8), blk, 0, stream>>>(e_wv, wvT, 768, 2048);
  conv_bf16_T<<<dim3(12,32,8), blk, 0, stream>>>(e_wg, wgT, 768, 2048);
  moe_gemm1_v6<<<2304, blk, 0, stream>>>(Amoe, wvT, wgT, e_bv, e_bg, eoff, hid);
  conv_bf16_T<<<dim3(32,12,8), blk, 0, stream>>>(e_wo, woT, 2048, 768);
  moe_gemm2_v6<<<864, blk, 0, stream>>>(hid, woT, e_bo, eoff, wgt, pout);
  moe_ln_final<<<1024, blk, 0, stream>>>(x2, pout, ppos, ffn_g, ffn_bn, out);
}